// Round 8
// baseline (534.300 us; speedup 1.0000x reference)
//
#include <hip/hip_runtime.h>
#include <stdint.h>

typedef __bf16 bf16;
typedef __attribute__((ext_vector_type(8))) __bf16 bf16x8;
typedef __attribute__((ext_vector_type(4))) float f32x4;

#define S_HW 16384
#define N_C 256

__device__ __forceinline__ f32x4 mfma16(bf16x8 a, bf16x8 b, f32x4 c) {
  return __builtin_amdgcn_mfma_f32_16x16x32_bf16(a, b, c, 0, 0, 0);
}
__device__ __forceinline__ void async_ld16(const bf16* g, bf16* l) {
  __builtin_amdgcn_global_load_lds(
      (const __attribute__((address_space(1))) unsigned int*)g,
      (__attribute__((address_space(3))) unsigned int*)l, 16, 0, 0);
}
__device__ __forceinline__ unsigned short bf2u(bf16 h) {
  union { bf16 h; unsigned short u; } c; c.h = h; return c.u;
}
__device__ __forceinline__ bf16 u2bf(unsigned short u) {
  union { unsigned short u; bf16 h; } c; c.u = u; return c.h;
}

// K1 v2: split x (f32) -> y_hi[b][c][s], y_lo, yt[b][s][hi|lo], Sx.
// 64c x 128s tile, 32 elems/thread, 64B contiguous store runs per stream.
__global__ __launch_bounds__(256) void k_split(
    const float* __restrict__ x, bf16* __restrict__ yhi, bf16* __restrict__ ylo,
    bf16* __restrict__ yt, float* __restrict__ Sx) {
  int b = blockIdx.z, c0 = blockIdx.y * 64, s0 = blockIdx.x * 128;
  __shared__ unsigned T[128][65];
  __shared__ float sxl[256];
  int t = threadIdx.x;
  int cl = t >> 2, sg = t & 3;
  size_t off = (size_t)(b * N_C + c0 + cl) * S_HW + s0 + sg * 32;
  const float* xp = x + off;
  bf16x8 hv[4], lv[4];
  float sum = 0.f;
#pragma unroll
  for (int i2 = 0; i2 < 8; i2++) {
    float4 v = *(const float4*)(xp + i2 * 4);
    float f4[4] = {v.x, v.y, v.z, v.w};
#pragma unroll
    for (int k = 0; k < 4; k++) {
      int i = i2 * 4 + k;
      float fv = f4[k];
      bf16 h = (bf16)fv;
      bf16 l = (bf16)(fv - (float)h);
      hv[i >> 3][i & 7] = h;
      lv[i >> 3][i & 7] = l;
      sum += fv;
      T[sg * 32 + i][cl] = (unsigned)bf2u(h) | ((unsigned)bf2u(l) << 16);
    }
  }
#pragma unroll
  for (int j = 0; j < 4; j++) {
    *(bf16x8*)(yhi + off + j * 8) = hv[j];
    *(bf16x8*)(ylo + off + j * 8) = lv[j];
  }
  sxl[t] = sum;
  __syncthreads();
  if (t < 64) {
    float s2 = sxl[t * 4] + sxl[t * 4 + 1] + sxl[t * 4 + 2] + sxl[t * 4 + 3];
    atomicAdd(&Sx[b * N_C + c0 + t], s2);
  }
  int sl = t >> 1, cg = t & 1;
  bf16x8 ho[4], lo2[4];
#pragma unroll
  for (int i = 0; i < 32; i++) {
    unsigned u = T[sl][cg * 32 + i];
    ho[i >> 3][i & 7] = u2bf((unsigned short)(u & 0xffffu));
    lo2[i >> 3][i & 7] = u2bf((unsigned short)(u >> 16));
  }
  size_t tb = (size_t)(b * S_HW + s0 + sl) * 512 + c0 + cg * 32;
#pragma unroll
  for (int j = 0; j < 4; j++) {
    *(bf16x8*)(yt + tb + j * 8) = ho[j];
    *(bf16x8*)(yt + tb + 256 + j * 8) = lo2[j];
  }
}

// K2: Gram partials. YG3[b][c][r'] = sum_s hi_c[s]*y_{r'}[s] (r'<256:hi, else lo)
// v2: 256x256 tile, BK=64, XOR slot-swizzle both sides, 512 thr / 8 waves,
// 2-buffer counted-vmcnt pipeline, setprio around MFMA cluster (T5).
__global__ __launch_bounds__(512, 2) void k_gram(
    const bf16* __restrict__ yhi, const bf16* __restrict__ ylo,
    float* __restrict__ YG3) {
  constexpr int BK = 64;
  constexpr int NT = 16;         // 1024 / BK
  constexpr int BUF = 256 * BK;  // 16384 elems = 32 KB
  __shared__ __align__(16) bf16 As[2 * BUF];  // 64 KB
  __shared__ __align__(16) bf16 Bs[2 * BUF];  // 64 KB
  int kc = blockIdx.x * 1024;
  int nsel = blockIdx.y;
  int b = blockIdx.z;
  int tid = threadIdx.x, lane = tid & 63, wave = tid >> 6;
  int wm = (wave >> 1) * 64, wn = (wave & 1) * 128;  // 4 M-waves x 2 N-waves
  const bf16* Ab = yhi + (size_t)(b * N_C) * S_HW;
  const bf16* Bb = (nsel == 0 ? yhi : ylo) + (size_t)(b * N_C) * S_HW;
  f32x4 acc[4][8] = {};
  int fm = lane & 15, cs = lane >> 4;

  // LDS slot s within a 128B row holds global slot (s ^ (row&7)).
  auto STAGE = [&](int bi, int t) {
    int kt = kc + t * BK;
#pragma unroll
    for (int i = 0; i < 4; i++) {
      int ch = i * 512 + tid;
      int row = ch >> 3, slot = ch & 7;
      int gcol = (slot ^ (row & 7)) * 8;
      async_ld16(Ab + (size_t)row * S_HW + kt + gcol, As + bi * BUF + ch * 8);
      async_ld16(Bb + (size_t)row * S_HW + kt + gcol, Bs + bi * BUF + ch * 8);
    }
  };

  STAGE(0, 0);
  STAGE(1, 1);
  int cur = 0;
  for (int t = 0; t < NT; t++) {
    if (t < NT - 1)
      asm volatile("s_waitcnt vmcnt(8)" ::: "memory");
    else
      asm volatile("s_waitcnt vmcnt(0)" ::: "memory");
    __builtin_amdgcn_s_barrier();
    const bf16* Ap = As + cur * BUF;
    const bf16* Bp = Bs + cur * BUF;
    bf16x8 af[4][2], bfr[8][2];
#pragma unroll
    for (int q = 0; q < 4; q++) {
      int ra = wm + q * 16 + fm;
#pragma unroll
      for (int h = 0; h < 2; h++)
        af[q][h] =
            *(const bf16x8*)(Ap + ra * BK + (((h << 2) | cs) ^ (ra & 7)) * 8);
    }
#pragma unroll
    for (int p = 0; p < 8; p++) {
      int rb = wn + p * 16 + fm;
#pragma unroll
      for (int h = 0; h < 2; h++)
        bfr[p][h] =
            *(const bf16x8*)(Bp + rb * BK + (((h << 2) | cs) ^ (rb & 7)) * 8);
    }
    asm volatile("s_waitcnt lgkmcnt(0)" ::: "memory");
    __builtin_amdgcn_sched_barrier(0);
    __builtin_amdgcn_s_barrier();
    if (t + 2 < NT) STAGE(cur, t + 2);
    __builtin_amdgcn_sched_barrier(0);
    __builtin_amdgcn_s_setprio(1);
#pragma unroll
    for (int q = 0; q < 4; q++)
#pragma unroll
      for (int p = 0; p < 8; p++) {
        acc[q][p] = mfma16(af[q][0], bfr[p][0], acc[q][p]);
        acc[q][p] = mfma16(af[q][1], bfr[p][1], acc[q][p]);
      }
    __builtin_amdgcn_s_setprio(0);
    cur ^= 1;
  }
  int quad = lane >> 4, cn = lane & 15;
  float* yg = YG3 + (size_t)(b * N_C) * 512 + nsel * 256;
#pragma unroll
  for (int q = 0; q < 4; q++)
#pragma unroll
    for (int r = 0; r < 4; r++) {
      int m = wm + q * 16 + quad * 4 + r;
#pragma unroll
      for (int p = 0; p < 8; p++) {
        int n = wn + p * 16 + cn;
        atomicAdd(&yg[(size_t)m * 512 + n], acc[q][p][r]);
      }
    }
}

// K3: WkT[k][j] = qkv_w[(256+j)][k]
__global__ __launch_bounds__(256) void k_wkt(const float* __restrict__ qkv_w,
                                             float* __restrict__ WkT) {
  int k = blockIdx.x, j = threadIdx.x;
  WkT[k * 256 + j] = qkv_w[(256 + j) * 256 + k];
}

// K4: GN coefs a,b (role 0) + u rows (roles 1..8, 64 rows each).
__global__ __launch_bounds__(256) void k_coefs(
    const float* __restrict__ Sx, const float* __restrict__ YG3,
    const float* __restrict__ gn_w, const float* __restrict__ gn_b,
    const float* __restrict__ qkv_w, const float* __restrict__ qkv_b,
    float* __restrict__ a_, float* __restrict__ bv_, float* __restrict__ u_,
    float* __restrict__ vbe) {
  int b = blockIdx.x, role = blockIdx.y, t = threadIdx.x;
  __shared__ float sxl[256], gxd[256], gm[32], gr[32], sh[256], bl[256];
  __shared__ float ured[64][4];
  sxl[t] = Sx[b * N_C + t];
  gxd[t] = YG3[(size_t)(b * N_C + t) * 512 + t] +
           2.f * YG3[(size_t)(b * N_C + t) * 512 + 256 + t];
  __syncthreads();
  if (t < 32) {
    float s = 0.f, q2 = 0.f;
#pragma unroll
    for (int i = 0; i < 8; i++) { s += sxl[t * 8 + i]; q2 += gxd[t * 8 + i]; }
    float mean = s * (1.f / 131072.f);
    float var = q2 * (1.f / 131072.f) - mean * mean;
    gm[t] = mean;
    gr[t] = 1.f / sqrtf(var + 1e-5f);
  }
  __syncthreads();
  {
    float A = gn_w[t] * gr[t >> 3];
    float B = gn_b[t] - gm[t >> 3] * A;
    bl[t] = B;
    sh[t] = A * sxl[t] + 16384.f * B;
    if (role == 0) {
      a_[b * N_C + t] = A;
      bv_[b * N_C + t] = B;
    }
  }
  __syncthreads();
  if (role == 0) {
    const float* wp = qkv_w + (size_t)(512 + t) * 256;
    float acc = 0.f;
    for (int c = 0; c < 256; c++) acc += wp[c] * bl[c];
    vbe[b * N_C + t] = acc + qkv_b[512 + t];
  } else {
    int r = (role - 1) * 64 + (t >> 2);
    int seg = (t & 3) * 64;
    const float* wp = qkv_w + (size_t)r * 256 + seg;
    float p = 0.f;
    for (int c = 0; c < 64; c++) p += wp[c] * sh[seg + c];
    ured[t >> 2][t & 3] = p;
    __syncthreads();
    if (t < 64)
      u_[b * 512 + (role - 1) * 64 + t] =
          ured[t][0] + ured[t][1] + ured[t][2] + ured[t][3];
  }
}

// K5: T1[b] = G_h[b] * WkT, G_h assembled inline from YG3 + affine coefs.
__global__ __launch_bounds__(256) void k_t1(
    const float* __restrict__ YG3, const float* __restrict__ WkT,
    const float* __restrict__ a_, const float* __restrict__ bv_,
    const float* __restrict__ Sx, float* __restrict__ T1) {
  int tile = blockIdx.x, b = blockIdx.y;
  int i0 = (tile >> 2) * 64, j0 = (tile & 3) * 64;
  __shared__ float As[64][69];
  __shared__ float Bs[64][69];
  __shared__ float al[256], bl[256], sxl[256];
  int t = threadIdx.x;
  al[t] = a_[b * N_C + t];
  bl[t] = bv_[b * N_C + t];
  sxl[t] = Sx[b * N_C + t];
  int cl = t >> 2, qq = (t & 3) * 16;
  int kk = t >> 2, jj = (t & 3) * 16;
  int ti = t >> 4, tj = t & 15;
  float acc[4][4] = {};
  for (int kc = 0; kc < 256; kc += 64) {
    {  // A1: row part of Gx: hh + hl
      const float* yg = YG3 + (size_t)(b * N_C + i0 + cl) * 512 + kc + qq;
#pragma unroll
      for (int i = 0; i < 16; i++) As[cl][qq + i] = yg[i] + yg[256 + i];
    }
    __syncthreads();
    {  // A2: += lh (transposed hl)
      int cp = kc + kk;
      const float* ygp = YG3 + (size_t)(b * N_C + cp) * 512 + 256 + i0 + jj;
#pragma unroll
      for (int i = 0; i < 16; i++) As[jj + i][kk] += ygp[i];
    }
    __syncthreads();
    {  // A3: affine -> G_h
      int c = i0 + cl;
      float ac = al[c], bc = bl[c], sxc = sxl[c];
#pragma unroll
      for (int i = 0; i < 16; i++) {
        int cp = kc + qq + i;
        As[cl][qq + i] = ac * al[cp] * As[cl][qq + i] + ac * bl[cp] * sxc +
                         bc * al[cp] * sxl[cp] + 16384.f * bc * bl[cp];
      }
    }
    {  // B: WkT chunk
      const float* wp = WkT + (size_t)(kc + kk) * 256 + j0 + jj;
#pragma unroll
      for (int i = 0; i < 16; i += 4) {
        float4 v = *(const float4*)(wp + i);
        Bs[kk][jj + i] = v.x; Bs[kk][jj + i + 1] = v.y;
        Bs[kk][jj + i + 2] = v.z; Bs[kk][jj + i + 3] = v.w;
      }
    }
    __syncthreads();
    for (int k = 0; k < 64; k++) {
      float av[4], bv4[4];
#pragma unroll
      for (int ii = 0; ii < 4; ii++) av[ii] = As[ti * 4 + ii][k];
#pragma unroll
      for (int j2 = 0; j2 < 4; j2++) bv4[j2] = Bs[k][tj * 4 + j2];
#pragma unroll
      for (int ii = 0; ii < 4; ii++)
#pragma unroll
        for (int j2 = 0; j2 < 4; j2++) acc[ii][j2] += av[ii] * bv4[j2];
    }
    __syncthreads();
  }
#pragma unroll
  for (int ii = 0; ii < 4; ii++)
#pragma unroll
    for (int j2 = 0; j2 < 4; j2++)
      T1[(size_t)(b * N_C + i0 + ti * 4 + ii) * 256 + j0 + tj * 4 + j2] =
          acc[ii][j2];
}

// K6: logits (Wq*T1 cols + bias terms), softmax -> attn[b][h][32][32]
__global__ __launch_bounds__(256) void k_logits(
    const float* __restrict__ T1, const float* __restrict__ qkv_w,
    const float* __restrict__ qkv_b, const float* __restrict__ u_,
    float* __restrict__ attn) {
  int h = blockIdx.x, b = blockIdx.y;
  __shared__ float Tc[64][33];
  __shared__ float Wql[32][65];
  __shared__ float Ll[32][33];
  __shared__ float uq[32], uk[32], bq[32], bk[32];
  int t = threadIdx.x;
  if (t < 32) {
    uq[t] = u_[b * 512 + h * 32 + t];
    uk[t] = u_[b * 512 + 256 + h * 32 + t];
    bq[t] = qkv_b[h * 32 + t];
    bk[t] = qkv_b[256 + h * 32 + t];
  }
  int i = t & 31, jg = t >> 5;
  float acc[4] = {};
  for (int cc = 0; cc < 256; cc += 64) {
    {
      int c_l = t >> 2, seg = (t & 3) * 8;
      const float* tp = T1 + (size_t)(b * N_C + cc + c_l) * 256 + h * 32 + seg;
      float4 v0 = *(const float4*)tp, v1 = *(const float4*)(tp + 4);
      Tc[c_l][seg] = v0.x; Tc[c_l][seg + 1] = v0.y;
      Tc[c_l][seg + 2] = v0.z; Tc[c_l][seg + 3] = v0.w;
      Tc[c_l][seg + 4] = v1.x; Tc[c_l][seg + 5] = v1.y;
      Tc[c_l][seg + 6] = v1.z; Tc[c_l][seg + 7] = v1.w;
      int row = t >> 3, seg2 = (t & 7) * 8;
      const float* wp = qkv_w + (size_t)(h * 32 + row) * 256 + cc + seg2;
      float4 w0 = *(const float4*)wp, w1 = *(const float4*)(wp + 4);
      Wql[row][seg2] = w0.x; Wql[row][seg2 + 1] = w0.y;
      Wql[row][seg2 + 2] = w0.z; Wql[row][seg2 + 3] = w0.w;
      Wql[row][seg2 + 4] = w1.x; Wql[row][seg2 + 5] = w1.y;
      Wql[row][seg2 + 6] = w1.z; Wql[row][seg2 + 7] = w1.w;
    }
    __syncthreads();
    for (int c = 0; c < 64; c++) {
      float w = Wql[i][c];
#pragma unroll
      for (int j2 = 0; j2 < 4; j2++) acc[j2] += w * Tc[c][jg * 4 + j2];
    }
    __syncthreads();
  }
  const float scale = 0.17677669529663687f;
#pragma unroll
  for (int j2 = 0; j2 < 4; j2++) {
    int j = jg * 4 + j2;
    Ll[i][j] = scale * (acc[j2] + bq[i] * uk[j] + bk[j] * uq[i] +
                        16384.f * bq[i] * bk[j]);
  }
  __syncthreads();
  if (t < 32) {
    float m = -1e30f;
    for (int j = 0; j < 32; j++) m = fmaxf(m, Ll[t][j]);
    float e[32], s = 0.f;
    for (int j = 0; j < 32; j++) { e[j] = expf(Ll[t][j] - m); s += e[j]; }
    float inv = 1.f / s;
    float* ap = attn + (size_t)((b * 8 + h) * 32 + t) * 32;
    for (int j = 0; j < 32; j++) ap[j] = e[j] * inv;
  }
}

// K7 (fused k_m1+k_m2+k_fa): per 64x64 tile of M2 = (P*blockdiag(attn))*Wv,
// with As (=M1 tile) computed on the fly; epilogue applies diag(a), +I,
// hi/lo split -> FA; g = M1*vbe + proj_b accumulated during As production.
__global__ __launch_bounds__(256) void k_pv(
    const float* __restrict__ proj_w, const float* __restrict__ attn,
    const float* __restrict__ qkv_w, const float* __restrict__ a_,
    const float* __restrict__ vbe, const float* __restrict__ proj_b,
    bf16* __restrict__ FA, float* __restrict__ g_) {
  int tile = blockIdx.x, b = blockIdx.y;
  int i0 = (tile >> 2) * 64, j0 = (tile & 3) * 64;
  __shared__ float As[64][69];
  __shared__ float Bs[64][69];
  __shared__ float At[2][32][33];
  __shared__ float gred[64][4];
  int t = threadIdx.x;
  int cl = t >> 2, qq = (t & 3) * 16;
  int kk = t >> 2, jj = (t & 3) * 16;
  int ti = t >> 4, tj = t & 15;
  float acc[4][4] = {};
  float gacc = 0.f;
  for (int kc = 0; kc < 256; kc += 64) {
    int h0 = kc >> 5;
    __syncthreads();
    {  // stage attn (2 heads) + Bs (Wv chunk)
      const float* ap = attn + (size_t)b * 8192 + h0 * 1024;
#pragma unroll
      for (int i = 0; i < 8; i++) {
        int idx = t * 8 + i;
        At[idx >> 10][(idx >> 5) & 31][idx & 31] = ap[idx];
      }
      const float* wp = qkv_w + (size_t)(512 + kc + kk) * 256 + j0 + jj;
#pragma unroll
      for (int i = 0; i < 16; i += 4) {
        float4 v = *(const float4*)(wp + i);
        Bs[kk][jj + i] = v.x; Bs[kk][jj + i + 1] = v.y;
        Bs[kk][jj + i + 2] = v.z; Bs[kk][jj + i + 3] = v.w;
      }
    }
    __syncthreads();
    {  // As[cl][qq..qq+15] = M1 tile entries; accumulate g partials
      int hl = qq >> 5;
      int jbase = qq & 31;
      const float* pp = proj_w + (size_t)(i0 + cl) * 256 + (h0 + hl) * 32;
      float pr[32];
#pragma unroll
      for (int i = 0; i < 32; i += 4) {
        float4 v = *(const float4*)(pp + i);
        pr[i] = v.x; pr[i + 1] = v.y; pr[i + 2] = v.z; pr[i + 3] = v.w;
      }
#pragma unroll
      for (int i = 0; i < 16; i++) {
        int jm = jbase + i;
        float s = 0.f;
#pragma unroll
        for (int ii = 0; ii < 32; ii++) s += pr[ii] * At[hl][ii][jm];
        As[cl][qq + i] = s;
        gacc += s * vbe[b * N_C + kc + qq + i];
      }
    }
    __syncthreads();
    for (int k = 0; k < 64; k++) {
      float av[4], bv4[4];
#pragma unroll
      for (int ii = 0; ii < 4; ii++) av[ii] = As[ti * 4 + ii][k];
#pragma unroll
      for (int j2 = 0; j2 < 4; j2++) bv4[j2] = Bs[k][tj * 4 + j2];
#pragma unroll
      for (int ii = 0; ii < 4; ii++)
#pragma unroll
        for (int j2 = 0; j2 < 4; j2++) acc[ii][j2] += av[ii] * bv4[j2];
    }
  }
  __syncthreads();
  gred[cl][t & 3] = gacc;
  __syncthreads();
  if ((tile & 3) == 0 && t < 64)
    g_[b * N_C + i0 + t] =
        gred[t][0] + gred[t][1] + gred[t][2] + gred[t][3] + proj_b[i0 + t];
  float a4[4];
  {
    float4 v = *(const float4*)(a_ + b * N_C + j0 + tj * 4);
    a4[0] = v.x; a4[1] = v.y; a4[2] = v.z; a4[3] = v.w;
  }
#pragma unroll
  for (int ii = 0; ii < 4; ii++) {
    int row = i0 + ti * 4 + ii;
#pragma unroll
    for (int j2 = 0; j2 < 4; j2++) {
      int col = j0 + tj * 4 + j2;
      float f = acc[ii][j2] * a4[j2] + (row == col ? 1.0f : 0.0f);
      bf16 hi = (bf16)f;
      bf16 lo = (bf16)(f - (float)hi);
      FA[(size_t)(b * N_C + row) * 512 + col] = hi;
      FA[(size_t)(b * N_C + row) * 512 + 256 + col] = lo;
    }
  }
}

// K10: out[o][s] = (I+F)*y + g[o] via 3-term hi/lo MFMA (K=768 mapped).
// v3 + setprio: M=256 x N=128, BK=64, XOR slot-swizzle both sides,
// 512 threads / 8 waves, 3-buffer counted-vmcnt pipeline.
// OUTPUT IS FLOAT32 (reference output dtype).
__global__ __launch_bounds__(512) void k_final(
    const bf16* __restrict__ FA, const bf16* __restrict__ yt,
    const float* __restrict__ g_, float* __restrict__ out) {
  constexpr int BK = 64;
  constexpr int NT = 12;  // 768 / BK
  constexpr int BUFA = 256 * BK;  // elems
  constexpr int BUFB = 128 * BK;
  __shared__ __align__(16) bf16 As[3 * BUFA];  // 96 KB
  __shared__ __align__(16) bf16 Bs[3 * BUFB];  // 48 KB
  int b = blockIdx.z, n0 = blockIdx.x * 128;
  int tid = threadIdx.x, lane = tid & 63, wave = tid >> 6;
  int wm = (wave >> 1) * 64, wn = (wave & 1) * 64;  // 4 M-waves x 2 N-waves
  const bf16* Ab = FA + (size_t)b * N_C * 512;
  const bf16* Bb = yt + (size_t)(b * S_HW + n0) * 512;
  f32x4 acc[4][4] = {};
  int fm = lane & 15, cs = lane >> 4;  // cs = k-slot group (8 elems = 16B)

  // swizzle: LDS slot s within a row holds global slot (s ^ (row&7)).
  auto STAGE = [&](int bi, int t) {
    int kt = t * BK;
    int ka = (kt < 512) ? kt : kt - 512;
    int kb = (kt < 256) ? kt : kt - 256;
#pragma unroll
    for (int i = 0; i < 4; i++) {  // A: 2048 chunks of 16B
      int ch = i * 512 + tid;
      int row = ch >> 3, slot = ch & 7;
      int gcol = (slot ^ (row & 7)) * 8;
      async_ld16(Ab + (size_t)row * 512 + ka + gcol,
                 As + bi * BUFA + ch * 8);
    }
#pragma unroll
    for (int i = 0; i < 2; i++) {  // B: 1024 chunks
      int ch = i * 512 + tid;
      int row = ch >> 3, slot = ch & 7;
      int gcol = (slot ^ (row & 7)) * 8;
      async_ld16(Bb + (size_t)row * 512 + kb + gcol,
                 Bs + bi * BUFB + ch * 8);
    }
  };

  STAGE(0, 0);
  STAGE(1, 1);
  STAGE(2, 2);
  int bi = 0;
  for (int t = 0; t < NT - 2; t++) {
    asm volatile("s_waitcnt vmcnt(12)" ::: "memory");  // oldest stage done
    __builtin_amdgcn_s_barrier();
    const bf16* Ap = As + bi * BUFA;
    const bf16* Bp = Bs + bi * BUFB;
    bf16x8 af[4][2], bfr[4][2];
#pragma unroll
    for (int q = 0; q < 4; q++) {
      int ra = wm + q * 16 + fm;
      int rb = wn + q * 16 + fm;
#pragma unroll
      for (int h = 0; h < 2; h++) {
        af[q][h] = *(const bf16x8*)(Ap + ra * BK +
                                    (((h << 2) | cs) ^ (ra & 7)) * 8);
        bfr[q][h] = *(const bf16x8*)(Bp + rb * BK +
                                     (((h << 2) | cs) ^ (rb & 7)) * 8);
      }
    }
    asm volatile("s_waitcnt lgkmcnt(0)" ::: "memory");
    __builtin_amdgcn_sched_barrier(0);
    __builtin_amdgcn_s_barrier();
    if (t + 3 < NT) STAGE(bi, t + 3);
    __builtin_amdgcn_sched_barrier(0);
    __builtin_amdgcn_s_setprio(1);
#pragma unroll
    for (int ti = 0; ti < 4; ti++)
#pragma unroll
      for (int tj = 0; tj < 4; tj++) {
        acc[ti][tj] = mfma16(af[ti][0], bfr[tj][0], acc[ti][tj]);
        acc[ti][tj] = mfma16(af[ti][1], bfr[tj][1], acc[ti][tj]);
      }
    __builtin_amdgcn_s_setprio(0);
    bi = (bi == 2) ? 0 : bi + 1;
  }
#pragma unroll
  for (int pe = 0; pe < 2; pe++) {
    if (pe == 0)
      asm volatile("s_waitcnt vmcnt(6)" ::: "memory");
    else
      asm volatile("s_waitcnt vmcnt(0)" ::: "memory");
    __builtin_amdgcn_s_barrier();
    const bf16* Ap = As + bi * BUFA;
    const bf16* Bp = Bs + bi * BUFB;
    bf16x8 af[4][2], bfr[4][2];
#pragma unroll
    for (int q = 0; q < 4; q++) {
      int ra = wm + q * 16 + fm;
      int rb = wn + q * 16 + fm;
#pragma unroll
      for (int h = 0; h < 2; h++) {
        af[q][h] = *(const bf16x8*)(Ap + ra * BK +
                                    (((h << 2) | cs) ^ (ra & 7)) * 8);
        bfr[q][h] = *(const bf16x8*)(Bp + rb * BK +
                                     (((h << 2) | cs) ^ (rb & 7)) * 8);
      }
    }
#pragma unroll
    for (int ti = 0; ti < 4; ti++)
#pragma unroll
      for (int tj = 0; tj < 4; tj++) {
        acc[ti][tj] = mfma16(af[ti][0], bfr[tj][0], acc[ti][tj]);
        acc[ti][tj] = mfma16(af[ti][1], bfr[tj][1], acc[ti][tj]);
      }
    bi = (bi == 2) ? 0 : bi + 1;
  }
  int quad = lane >> 4, cn = lane & 15;
#pragma unroll
  for (int ti = 0; ti < 4; ti++)
#pragma unroll
    for (int r = 0; r < 4; r++) {
      int row = wm + ti * 16 + quad * 4 + r;
      float gb = g_[b * N_C + row];
#pragma unroll
      for (int tj = 0; tj < 4; tj++) {
        int col = n0 + wn + tj * 16 + cn;
        size_t idx = (size_t)(b * N_C + row) * S_HW + col;
        out[idx] = acc[ti][tj][r] + gb;
      }
    }
}

extern "C" void kernel_launch(void* const* d_in, const int* in_sizes, int n_in,
                              void* d_out, int out_size, void* d_ws,
                              size_t ws_size, hipStream_t stream) {
  const float* x = (const float*)d_in[0];
  const float* gn_w = (const float*)d_in[1];
  const float* gn_b = (const float*)d_in[2];
  const float* qkv_w = (const float*)d_in[3];
  const float* qkv_b = (const float*)d_in[4];
  const float* proj_w = (const float*)d_in[5];
  const float* proj_b = (const float*)d_in[6];
  float* out = (float*)d_out;  // reference output dtype is float32

  const size_t MB = 1ull << 20;
  char* ws = (char*)d_ws;
  bf16* ylo = (bf16*)ws;                              // 64 MB
  bf16* yt = (bf16*)(ws + 64 * MB);                   // 128 MB
  float* YG3 = (float*)(ws + 192 * MB);               // 4 MB (R1)
  bf16* FA = (bf16*)(ws + 194 * MB);                  // overlays YG3[2..4M)
  float* WkT = (float*)(ws + 196 * MB);               // 256 KB (R2)
  float* attn = (float*)(ws + 196 * MB + 256 * 1024); // 256 KB
  float* Sx = (float*)(ws + 196 * MB + 512 * 1024);   // 8 KB
  float* a_ = (float*)(ws + 196 * MB + 520 * 1024);   // 8 KB
  float* bv_ = (float*)(ws + 196 * MB + 528 * 1024);  // 8 KB
  float* u_ = (float*)(ws + 196 * MB + 536 * 1024);   // 16 KB
  float* vbe = (float*)(ws + 196 * MB + 552 * 1024);  // 8 KB
  float* g_ = (float*)(ws + 196 * MB + 560 * 1024);   // 8 KB
  float* T1 = (float*)(ws + 198 * MB);                // 2 MB (R3)
  bf16* yhi = (bf16*)d_out;  // 67 MB scratch in d_out; dead before k_final

  if (ws_size < 200 * MB) return;

  hipMemsetAsync(YG3, 0, 4 * MB + 520 * 1024, stream);
  k_split<<<dim3(128, 4, 8), 256, 0, stream>>>(x, yhi, ylo, yt, Sx);
  k_gram<<<dim3(16, 2, 8), 512, 0, stream>>>(yhi, ylo, YG3);
  k_wkt<<<256, 256, 0, stream>>>(qkv_w, WkT);
  k_coefs<<<dim3(8, 9), 256, 0, stream>>>(Sx, YG3, gn_w, gn_b, qkv_w, qkv_b,
                                          a_, bv_, u_, vbe);
  k_t1<<<dim3(16, 8), 256, 0, stream>>>(YG3, WkT, a_, bv_, Sx, T1);
  k_logits<<<dim3(8, 8), 256, 0, stream>>>(T1, qkv_w, qkv_b, u_, attn);
  k_pv<<<dim3(16, 8), 256, 0, stream>>>(proj_w, attn, qkv_w, a_, vbe, proj_b,
                                        FA, g_);
  k_final<<<dim3(128, 1, 8), 512, 0, stream>>>(FA, yt, g_, out);
}

// Round 9
// 514.924 us; speedup vs baseline: 1.0376x; 1.0376x over previous
//
#include <hip/hip_runtime.h>
#include <stdint.h>

typedef __bf16 bf16;
typedef __attribute__((ext_vector_type(8))) __bf16 bf16x8;
typedef __attribute__((ext_vector_type(4))) float f32x4;

#define S_HW 16384
#define N_C 256

__device__ __forceinline__ f32x4 mfma16(bf16x8 a, bf16x8 b, f32x4 c) {
  return __builtin_amdgcn_mfma_f32_16x16x32_bf16(a, b, c, 0, 0, 0);
}
__device__ __forceinline__ void async_ld16(const bf16* g, bf16* l) {
  __builtin_amdgcn_global_load_lds(
      (const __attribute__((address_space(1))) unsigned int*)g,
      (__attribute__((address_space(3))) unsigned int*)l, 16, 0, 0);
}
__device__ __forceinline__ unsigned short bf2u(bf16 h) {
  union { bf16 h; unsigned short u; } c; c.h = h; return c.u;
}
__device__ __forceinline__ bf16 u2bf(unsigned short u) {
  union { unsigned short u; bf16 h; } c; c.u = u; return c.h;
}

// K1 (v1, proven 103-108us): split x (f32) -> y_hi[b][c][s] (d_out scratch),
// y_lo (ws), yt[b][s][hi|lo] (ws), and per-(b,c) row sums Sx (atomic).
__global__ __launch_bounds__(256) void k_split(
    const float* __restrict__ x, bf16* __restrict__ yhi, bf16* __restrict__ ylo,
    bf16* __restrict__ yt, float* __restrict__ Sx) {
  int b = blockIdx.z, c0 = blockIdx.y * 64, s0 = blockIdx.x * 64;
  __shared__ unsigned T[64][65];
  __shared__ float sxl[256];
  int t = threadIdx.x;
  int cl = t >> 2, sg = t & 3;
  size_t off = (size_t)(b * N_C + c0 + cl) * S_HW + s0 + sg * 16;
  const float* xp = x + off;
  bf16x8 hv[2], lv[2];
  float sum = 0.f;
#pragma unroll
  for (int i2 = 0; i2 < 4; i2++) {
    float4 v = *(const float4*)(xp + i2 * 4);
    float f4[4] = {v.x, v.y, v.z, v.w};
#pragma unroll
    for (int k = 0; k < 4; k++) {
      int i = i2 * 4 + k;
      float fv = f4[k];
      bf16 h = (bf16)fv;
      bf16 l = (bf16)(fv - (float)h);
      hv[i >> 3][i & 7] = h;
      lv[i >> 3][i & 7] = l;
      sum += fv;
      T[sg * 16 + i][cl] = (unsigned)bf2u(h) | ((unsigned)bf2u(l) << 16);
    }
  }
  *(bf16x8*)(yhi + off) = hv[0];
  *(bf16x8*)(yhi + off + 8) = hv[1];
  *(bf16x8*)(ylo + off) = lv[0];
  *(bf16x8*)(ylo + off + 8) = lv[1];
  sxl[t] = sum;
  __syncthreads();
  if (t < 64) {
    float s2 = sxl[t * 4] + sxl[t * 4 + 1] + sxl[t * 4 + 2] + sxl[t * 4 + 3];
    atomicAdd(&Sx[b * N_C + c0 + t], s2);
  }
  int sl = t >> 2, cg = t & 3;
  bf16x8 ho[2], lo2[2];
#pragma unroll
  for (int i = 0; i < 16; i++) {
    unsigned u = T[sl][cg * 16 + i];
    ho[i >> 3][i & 7] = u2bf((unsigned short)(u & 0xffffu));
    lo2[i >> 3][i & 7] = u2bf((unsigned short)(u >> 16));
  }
  size_t tb = (size_t)(b * S_HW + s0 + sl) * 512 + c0 + cg * 16;
  *(bf16x8*)(yt + tb) = ho[0];
  *(bf16x8*)(yt + tb + 8) = ho[1];
  *(bf16x8*)(yt + tb + 256) = lo2[0];
  *(bf16x8*)(yt + tb + 256 + 8) = lo2[1];
}

// K2: Gram partials. YG3[b][c][r'] = sum_s hi_c[s]*y_{r'}[s] (r'<256:hi, else lo)
// v2: 256x256 tile, BK=64, XOR slot-swizzle both sides, 512 thr / 8 waves,
// 2-buffer counted-vmcnt pipeline, setprio around MFMA cluster (T5).
__global__ __launch_bounds__(512, 2) void k_gram(
    const bf16* __restrict__ yhi, const bf16* __restrict__ ylo,
    float* __restrict__ YG3) {
  constexpr int BK = 64;
  constexpr int NT = 16;         // 1024 / BK
  constexpr int BUF = 256 * BK;  // 16384 elems = 32 KB
  __shared__ __align__(16) bf16 As[2 * BUF];  // 64 KB
  __shared__ __align__(16) bf16 Bs[2 * BUF];  // 64 KB
  int kc = blockIdx.x * 1024;
  int nsel = blockIdx.y;
  int b = blockIdx.z;
  int tid = threadIdx.x, lane = tid & 63, wave = tid >> 6;
  int wm = (wave >> 1) * 64, wn = (wave & 1) * 128;  // 4 M-waves x 2 N-waves
  const bf16* Ab = yhi + (size_t)(b * N_C) * S_HW;
  const bf16* Bb = (nsel == 0 ? yhi : ylo) + (size_t)(b * N_C) * S_HW;
  f32x4 acc[4][8] = {};
  int fm = lane & 15, cs = lane >> 4;

  // LDS slot s within a 128B row holds global slot (s ^ (row&7)).
  auto STAGE = [&](int bi, int t) {
    int kt = kc + t * BK;
#pragma unroll
    for (int i = 0; i < 4; i++) {
      int ch = i * 512 + tid;
      int row = ch >> 3, slot = ch & 7;
      int gcol = (slot ^ (row & 7)) * 8;
      async_ld16(Ab + (size_t)row * S_HW + kt + gcol, As + bi * BUF + ch * 8);
      async_ld16(Bb + (size_t)row * S_HW + kt + gcol, Bs + bi * BUF + ch * 8);
    }
  };

  STAGE(0, 0);
  STAGE(1, 1);
  int cur = 0;
  for (int t = 0; t < NT; t++) {
    if (t < NT - 1)
      asm volatile("s_waitcnt vmcnt(8)" ::: "memory");
    else
      asm volatile("s_waitcnt vmcnt(0)" ::: "memory");
    __builtin_amdgcn_s_barrier();
    const bf16* Ap = As + cur * BUF;
    const bf16* Bp = Bs + cur * BUF;
    bf16x8 af[4][2], bfr[8][2];
#pragma unroll
    for (int q = 0; q < 4; q++) {
      int ra = wm + q * 16 + fm;
#pragma unroll
      for (int h = 0; h < 2; h++)
        af[q][h] =
            *(const bf16x8*)(Ap + ra * BK + (((h << 2) | cs) ^ (ra & 7)) * 8);
    }
#pragma unroll
    for (int p = 0; p < 8; p++) {
      int rb = wn + p * 16 + fm;
#pragma unroll
      for (int h = 0; h < 2; h++)
        bfr[p][h] =
            *(const bf16x8*)(Bp + rb * BK + (((h << 2) | cs) ^ (rb & 7)) * 8);
    }
    asm volatile("s_waitcnt lgkmcnt(0)" ::: "memory");
    __builtin_amdgcn_sched_barrier(0);
    __builtin_amdgcn_s_barrier();
    if (t + 2 < NT) STAGE(cur, t + 2);
    __builtin_amdgcn_sched_barrier(0);
    __builtin_amdgcn_s_setprio(1);
#pragma unroll
    for (int q = 0; q < 4; q++)
#pragma unroll
      for (int p = 0; p < 8; p++) {
        acc[q][p] = mfma16(af[q][0], bfr[p][0], acc[q][p]);
        acc[q][p] = mfma16(af[q][1], bfr[p][1], acc[q][p]);
      }
    __builtin_amdgcn_s_setprio(0);
    cur ^= 1;
  }
  int quad = lane >> 4, cn = lane & 15;
  float* yg = YG3 + (size_t)(b * N_C) * 512 + nsel * 256;
#pragma unroll
  for (int q = 0; q < 4; q++)
#pragma unroll
    for (int r = 0; r < 4; r++) {
      int m = wm + q * 16 + quad * 4 + r;
#pragma unroll
      for (int p = 0; p < 8; p++) {
        int n = wn + p * 16 + cn;
        atomicAdd(&yg[(size_t)m * 512 + n], acc[q][p][r]);
      }
    }
}

// K3: WkT[k][j] = qkv_w[(256+j)][k]
__global__ __launch_bounds__(256) void k_wkt(const float* __restrict__ qkv_w,
                                             float* __restrict__ WkT) {
  int k = blockIdx.x, j = threadIdx.x;
  WkT[k * 256 + j] = qkv_w[(256 + j) * 256 + k];
}

// K4: GN coefs a,b (role 0) + u rows (roles 1..8, 64 rows each).
__global__ __launch_bounds__(256) void k_coefs(
    const float* __restrict__ Sx, const float* __restrict__ YG3,
    const float* __restrict__ gn_w, const float* __restrict__ gn_b,
    const float* __restrict__ qkv_w, const float* __restrict__ qkv_b,
    float* __restrict__ a_, float* __restrict__ bv_, float* __restrict__ u_,
    float* __restrict__ vbe) {
  int b = blockIdx.x, role = blockIdx.y, t = threadIdx.x;
  __shared__ float sxl[256], gxd[256], gm[32], gr[32], sh[256], bl[256];
  __shared__ float ured[64][4];
  sxl[t] = Sx[b * N_C + t];
  gxd[t] = YG3[(size_t)(b * N_C + t) * 512 + t] +
           2.f * YG3[(size_t)(b * N_C + t) * 512 + 256 + t];
  __syncthreads();
  if (t < 32) {
    float s = 0.f, q2 = 0.f;
#pragma unroll
    for (int i = 0; i < 8; i++) { s += sxl[t * 8 + i]; q2 += gxd[t * 8 + i]; }
    float mean = s * (1.f / 131072.f);
    float var = q2 * (1.f / 131072.f) - mean * mean;
    gm[t] = mean;
    gr[t] = 1.f / sqrtf(var + 1e-5f);
  }
  __syncthreads();
  {
    float A = gn_w[t] * gr[t >> 3];
    float B = gn_b[t] - gm[t >> 3] * A;
    bl[t] = B;
    sh[t] = A * sxl[t] + 16384.f * B;
    if (role == 0) {
      a_[b * N_C + t] = A;
      bv_[b * N_C + t] = B;
    }
  }
  __syncthreads();
  if (role == 0) {
    const float* wp = qkv_w + (size_t)(512 + t) * 256;
    float acc = 0.f;
    for (int c = 0; c < 256; c++) acc += wp[c] * bl[c];
    vbe[b * N_C + t] = acc + qkv_b[512 + t];
  } else {
    int r = (role - 1) * 64 + (t >> 2);
    int seg = (t & 3) * 64;
    const float* wp = qkv_w + (size_t)r * 256 + seg;
    float p = 0.f;
    for (int c = 0; c < 64; c++) p += wp[c] * sh[seg + c];
    ured[t >> 2][t & 3] = p;
    __syncthreads();
    if (t < 64)
      u_[b * 512 + (role - 1) * 64 + t] =
          ured[t][0] + ured[t][1] + ured[t][2] + ured[t][3];
  }
}

// K5: T1[b] = G_h[b] * WkT, G_h assembled inline from YG3 + affine coefs.
__global__ __launch_bounds__(256) void k_t1(
    const float* __restrict__ YG3, const float* __restrict__ WkT,
    const float* __restrict__ a_, const float* __restrict__ bv_,
    const float* __restrict__ Sx, float* __restrict__ T1) {
  int tile = blockIdx.x, b = blockIdx.y;
  int i0 = (tile >> 2) * 64, j0 = (tile & 3) * 64;
  __shared__ float As[64][69];
  __shared__ float Bs[64][69];
  __shared__ float al[256], bl[256], sxl[256];
  int t = threadIdx.x;
  al[t] = a_[b * N_C + t];
  bl[t] = bv_[b * N_C + t];
  sxl[t] = Sx[b * N_C + t];
  int cl = t >> 2, qq = (t & 3) * 16;
  int kk = t >> 2, jj = (t & 3) * 16;
  int ti = t >> 4, tj = t & 15;
  float acc[4][4] = {};
  for (int kc = 0; kc < 256; kc += 64) {
    {  // A1: row part of Gx: hh + hl
      const float* yg = YG3 + (size_t)(b * N_C + i0 + cl) * 512 + kc + qq;
#pragma unroll
      for (int i = 0; i < 16; i++) As[cl][qq + i] = yg[i] + yg[256 + i];
    }
    __syncthreads();
    {  // A2: += lh (transposed hl)
      int cp = kc + kk;
      const float* ygp = YG3 + (size_t)(b * N_C + cp) * 512 + 256 + i0 + jj;
#pragma unroll
      for (int i = 0; i < 16; i++) As[jj + i][kk] += ygp[i];
    }
    __syncthreads();
    {  // A3: affine -> G_h
      int c = i0 + cl;
      float ac = al[c], bc = bl[c], sxc = sxl[c];
#pragma unroll
      for (int i = 0; i < 16; i++) {
        int cp = kc + qq + i;
        As[cl][qq + i] = ac * al[cp] * As[cl][qq + i] + ac * bl[cp] * sxc +
                         bc * al[cp] * sxl[cp] + 16384.f * bc * bl[cp];
      }
    }
    {  // B: WkT chunk
      const float* wp = WkT + (size_t)(kc + kk) * 256 + j0 + jj;
#pragma unroll
      for (int i = 0; i < 16; i += 4) {
        float4 v = *(const float4*)(wp + i);
        Bs[kk][jj + i] = v.x; Bs[kk][jj + i + 1] = v.y;
        Bs[kk][jj + i + 2] = v.z; Bs[kk][jj + i + 3] = v.w;
      }
    }
    __syncthreads();
    for (int k = 0; k < 64; k++) {
      float av[4], bv4[4];
#pragma unroll
      for (int ii = 0; ii < 4; ii++) av[ii] = As[ti * 4 + ii][k];
#pragma unroll
      for (int j2 = 0; j2 < 4; j2++) bv4[j2] = Bs[k][tj * 4 + j2];
#pragma unroll
      for (int ii = 0; ii < 4; ii++)
#pragma unroll
        for (int j2 = 0; j2 < 4; j2++) acc[ii][j2] += av[ii] * bv4[j2];
    }
    __syncthreads();
  }
#pragma unroll
  for (int ii = 0; ii < 4; ii++)
#pragma unroll
    for (int j2 = 0; j2 < 4; j2++)
      T1[(size_t)(b * N_C + i0 + ti * 4 + ii) * 256 + j0 + tj * 4 + j2] =
          acc[ii][j2];
}

// K6: logits (Wq*T1 cols + bias terms), softmax -> attn[b][h][32][32]
__global__ __launch_bounds__(256) void k_logits(
    const float* __restrict__ T1, const float* __restrict__ qkv_w,
    const float* __restrict__ qkv_b, const float* __restrict__ u_,
    float* __restrict__ attn) {
  int h = blockIdx.x, b = blockIdx.y;
  __shared__ float Tc[64][33];
  __shared__ float Wql[32][65];
  __shared__ float Ll[32][33];
  __shared__ float uq[32], uk[32], bq[32], bk[32];
  int t = threadIdx.x;
  if (t < 32) {
    uq[t] = u_[b * 512 + h * 32 + t];
    uk[t] = u_[b * 512 + 256 + h * 32 + t];
    bq[t] = qkv_b[h * 32 + t];
    bk[t] = qkv_b[256 + h * 32 + t];
  }
  int i = t & 31, jg = t >> 5;
  float acc[4] = {};
  for (int cc = 0; cc < 256; cc += 64) {
    {
      int c_l = t >> 2, seg = (t & 3) * 8;
      const float* tp = T1 + (size_t)(b * N_C + cc + c_l) * 256 + h * 32 + seg;
      float4 v0 = *(const float4*)tp, v1 = *(const float4*)(tp + 4);
      Tc[c_l][seg] = v0.x; Tc[c_l][seg + 1] = v0.y;
      Tc[c_l][seg + 2] = v0.z; Tc[c_l][seg + 3] = v0.w;
      Tc[c_l][seg + 4] = v1.x; Tc[c_l][seg + 5] = v1.y;
      Tc[c_l][seg + 6] = v1.z; Tc[c_l][seg + 7] = v1.w;
      int row = t >> 3, seg2 = (t & 7) * 8;
      const float* wp = qkv_w + (size_t)(h * 32 + row) * 256 + cc + seg2;
      float4 w0 = *(const float4*)wp, w1 = *(const float4*)(wp + 4);
      Wql[row][seg2] = w0.x; Wql[row][seg2 + 1] = w0.y;
      Wql[row][seg2 + 2] = w0.z; Wql[row][seg2 + 3] = w0.w;
      Wql[row][seg2 + 4] = w1.x; Wql[row][seg2 + 5] = w1.y;
      Wql[row][seg2 + 6] = w1.z; Wql[row][seg2 + 7] = w1.w;
    }
    __syncthreads();
    for (int c = 0; c < 64; c++) {
      float w = Wql[i][c];
#pragma unroll
      for (int j2 = 0; j2 < 4; j2++) acc[j2] += w * Tc[c][jg * 4 + j2];
    }
    __syncthreads();
  }
  const float scale = 0.17677669529663687f;
#pragma unroll
  for (int j2 = 0; j2 < 4; j2++) {
    int j = jg * 4 + j2;
    Ll[i][j] = scale * (acc[j2] + bq[i] * uk[j] + bk[j] * uq[i] +
                        16384.f * bq[i] * bk[j]);
  }
  __syncthreads();
  if (t < 32) {
    float m = -1e30f;
    for (int j = 0; j < 32; j++) m = fmaxf(m, Ll[t][j]);
    float e[32], s = 0.f;
    for (int j = 0; j < 32; j++) { e[j] = expf(Ll[t][j] - m); s += e[j]; }
    float inv = 1.f / s;
    float* ap = attn + (size_t)((b * 8 + h) * 32 + t) * 32;
    for (int j = 0; j < 32; j++) ap[j] = e[j] * inv;
  }
}

// K7 (fused k_m1+k_m2+k_fa): per 64x64 tile of M2 = (P*blockdiag(attn))*Wv,
// with As (=M1 tile) computed on the fly; epilogue applies diag(a), +I,
// hi/lo split -> FA; g = M1*vbe + proj_b accumulated during As production.
__global__ __launch_bounds__(256) void k_pv(
    const float* __restrict__ proj_w, const float* __restrict__ attn,
    const float* __restrict__ qkv_w, const float* __restrict__ a_,
    const float* __restrict__ vbe, const float* __restrict__ proj_b,
    bf16* __restrict__ FA, float* __restrict__ g_) {
  int tile = blockIdx.x, b = blockIdx.y;
  int i0 = (tile >> 2) * 64, j0 = (tile & 3) * 64;
  __shared__ float As[64][69];
  __shared__ float Bs[64][69];
  __shared__ float At[2][32][33];
  __shared__ float gred[64][4];
  int t = threadIdx.x;
  int cl = t >> 2, qq = (t & 3) * 16;
  int kk = t >> 2, jj = (t & 3) * 16;
  int ti = t >> 4, tj = t & 15;
  float acc[4][4] = {};
  float gacc = 0.f;
  for (int kc = 0; kc < 256; kc += 64) {
    int h0 = kc >> 5;
    __syncthreads();
    {  // stage attn (2 heads) + Bs (Wv chunk)
      const float* ap = attn + (size_t)b * 8192 + h0 * 1024;
#pragma unroll
      for (int i = 0; i < 8; i++) {
        int idx = t * 8 + i;
        At[idx >> 10][(idx >> 5) & 31][idx & 31] = ap[idx];
      }
      const float* wp = qkv_w + (size_t)(512 + kc + kk) * 256 + j0 + jj;
#pragma unroll
      for (int i = 0; i < 16; i += 4) {
        float4 v = *(const float4*)(wp + i);
        Bs[kk][jj + i] = v.x; Bs[kk][jj + i + 1] = v.y;
        Bs[kk][jj + i + 2] = v.z; Bs[kk][jj + i + 3] = v.w;
      }
    }
    __syncthreads();
    {  // As[cl][qq..qq+15] = M1 tile entries; accumulate g partials
      int hl = qq >> 5;
      int jbase = qq & 31;
      const float* pp = proj_w + (size_t)(i0 + cl) * 256 + (h0 + hl) * 32;
      float pr[32];
#pragma unroll
      for (int i = 0; i < 32; i += 4) {
        float4 v = *(const float4*)(pp + i);
        pr[i] = v.x; pr[i + 1] = v.y; pr[i + 2] = v.z; pr[i + 3] = v.w;
      }
#pragma unroll
      for (int i = 0; i < 16; i++) {
        int jm = jbase + i;
        float s = 0.f;
#pragma unroll
        for (int ii = 0; ii < 32; ii++) s += pr[ii] * At[hl][ii][jm];
        As[cl][qq + i] = s;
        gacc += s * vbe[b * N_C + kc + qq + i];
      }
    }
    __syncthreads();
    for (int k = 0; k < 64; k++) {
      float av[4], bv4[4];
#pragma unroll
      for (int ii = 0; ii < 4; ii++) av[ii] = As[ti * 4 + ii][k];
#pragma unroll
      for (int j2 = 0; j2 < 4; j2++) bv4[j2] = Bs[k][tj * 4 + j2];
#pragma unroll
      for (int ii = 0; ii < 4; ii++)
#pragma unroll
        for (int j2 = 0; j2 < 4; j2++) acc[ii][j2] += av[ii] * bv4[j2];
    }
  }
  __syncthreads();
  gred[cl][t & 3] = gacc;
  __syncthreads();
  if ((tile & 3) == 0 && t < 64)
    g_[b * N_C + i0 + t] =
        gred[t][0] + gred[t][1] + gred[t][2] + gred[t][3] + proj_b[i0 + t];
  float a4[4];
  {
    float4 v = *(const float4*)(a_ + b * N_C + j0 + tj * 4);
    a4[0] = v.x; a4[1] = v.y; a4[2] = v.z; a4[3] = v.w;
  }
#pragma unroll
  for (int ii = 0; ii < 4; ii++) {
    int row = i0 + ti * 4 + ii;
#pragma unroll
    for (int j2 = 0; j2 < 4; j2++) {
      int col = j0 + tj * 4 + j2;
      float f = acc[ii][j2] * a4[j2] + (row == col ? 1.0f : 0.0f);
      bf16 hi = (bf16)f;
      bf16 lo = (bf16)(f - (float)hi);
      FA[(size_t)(b * N_C + row) * 512 + col] = hi;
      FA[(size_t)(b * N_C + row) * 512 + 256 + col] = lo;
    }
  }
}

// K10: out[o][s] = (I+F)*y + g[o] via 3-term hi/lo MFMA (K=768 mapped).
// v3 + setprio: M=256 x N=128, BK=64, XOR slot-swizzle both sides,
// 512 threads / 8 waves, 3-buffer counted-vmcnt pipeline.
// OUTPUT IS FLOAT32 (reference output dtype).
__global__ __launch_bounds__(512) void k_final(
    const bf16* __restrict__ FA, const bf16* __restrict__ yt,
    const float* __restrict__ g_, float* __restrict__ out) {
  constexpr int BK = 64;
  constexpr int NT = 12;  // 768 / BK
  constexpr int BUFA = 256 * BK;  // elems
  constexpr int BUFB = 128 * BK;
  __shared__ __align__(16) bf16 As[3 * BUFA];  // 96 KB
  __shared__ __align__(16) bf16 Bs[3 * BUFB];  // 48 KB
  int b = blockIdx.z, n0 = blockIdx.x * 128;
  int tid = threadIdx.x, lane = tid & 63, wave = tid >> 6;
  int wm = (wave >> 1) * 64, wn = (wave & 1) * 64;  // 4 M-waves x 2 N-waves
  const bf16* Ab = FA + (size_t)b * N_C * 512;
  const bf16* Bb = yt + (size_t)(b * S_HW + n0) * 512;
  f32x4 acc[4][4] = {};
  int fm = lane & 15, cs = lane >> 4;  // cs = k-slot group (8 elems = 16B)

  // swizzle: LDS slot s within a row holds global slot (s ^ (row&7)).
  auto STAGE = [&](int bi, int t) {
    int kt = t * BK;
    int ka = (kt < 512) ? kt : kt - 512;
    int kb = (kt < 256) ? kt : kt - 256;
#pragma unroll
    for (int i = 0; i < 4; i++) {  // A: 2048 chunks of 16B
      int ch = i * 512 + tid;
      int row = ch >> 3, slot = ch & 7;
      int gcol = (slot ^ (row & 7)) * 8;
      async_ld16(Ab + (size_t)row * 512 + ka + gcol,
                 As + bi * BUFA + ch * 8);
    }
#pragma unroll
    for (int i = 0; i < 2; i++) {  // B: 1024 chunks
      int ch = i * 512 + tid;
      int row = ch >> 3, slot = ch & 7;
      int gcol = (slot ^ (row & 7)) * 8;
      async_ld16(Bb + (size_t)row * 512 + kb + gcol,
                 Bs + bi * BUFB + ch * 8);
    }
  };

  STAGE(0, 0);
  STAGE(1, 1);
  STAGE(2, 2);
  int bi = 0;
  for (int t = 0; t < NT - 2; t++) {
    asm volatile("s_waitcnt vmcnt(12)" ::: "memory");  // oldest stage done
    __builtin_amdgcn_s_barrier();
    const bf16* Ap = As + bi * BUFA;
    const bf16* Bp = Bs + bi * BUFB;
    bf16x8 af[4][2], bfr[4][2];
#pragma unroll
    for (int q = 0; q < 4; q++) {
      int ra = wm + q * 16 + fm;
      int rb = wn + q * 16 + fm;
#pragma unroll
      for (int h = 0; h < 2; h++) {
        af[q][h] = *(const bf16x8*)(Ap + ra * BK +
                                    (((h << 2) | cs) ^ (ra & 7)) * 8);
        bfr[q][h] = *(const bf16x8*)(Bp + rb * BK +
                                     (((h << 2) | cs) ^ (rb & 7)) * 8);
      }
    }
    asm volatile("s_waitcnt lgkmcnt(0)" ::: "memory");
    __builtin_amdgcn_sched_barrier(0);
    __builtin_amdgcn_s_barrier();
    if (t + 3 < NT) STAGE(bi, t + 3);
    __builtin_amdgcn_sched_barrier(0);
    __builtin_amdgcn_s_setprio(1);
#pragma unroll
    for (int ti = 0; ti < 4; ti++)
#pragma unroll
      for (int tj = 0; tj < 4; tj++) {
        acc[ti][tj] = mfma16(af[ti][0], bfr[tj][0], acc[ti][tj]);
        acc[ti][tj] = mfma16(af[ti][1], bfr[tj][1], acc[ti][tj]);
      }
    __builtin_amdgcn_s_setprio(0);
    bi = (bi == 2) ? 0 : bi + 1;
  }
#pragma unroll
  for (int pe = 0; pe < 2; pe++) {
    if (pe == 0)
      asm volatile("s_waitcnt vmcnt(6)" ::: "memory");
    else
      asm volatile("s_waitcnt vmcnt(0)" ::: "memory");
    __builtin_amdgcn_s_barrier();
    const bf16* Ap = As + bi * BUFA;
    const bf16* Bp = Bs + bi * BUFB;
    bf16x8 af[4][2], bfr[4][2];
#pragma unroll
    for (int q = 0; q < 4; q++) {
      int ra = wm + q * 16 + fm;
      int rb = wn + q * 16 + fm;
#pragma unroll
      for (int h = 0; h < 2; h++) {
        af[q][h] = *(const bf16x8*)(Ap + ra * BK +
                                    (((h << 2) | cs) ^ (ra & 7)) * 8);
        bfr[q][h] = *(const bf16x8*)(Bp + rb * BK +
                                     (((h << 2) | cs) ^ (rb & 7)) * 8);
      }
    }
#pragma unroll
    for (int ti = 0; ti < 4; ti++)
#pragma unroll
      for (int tj = 0; tj < 4; tj++) {
        acc[ti][tj] = mfma16(af[ti][0], bfr[tj][0], acc[ti][tj]);
        acc[ti][tj] = mfma16(af[ti][1], bfr[tj][1], acc[ti][tj]);
      }
    bi = (bi == 2) ? 0 : bi + 1;
  }
  int quad = lane >> 4, cn = lane & 15;
#pragma unroll
  for (int ti = 0; ti < 4; ti++)
#pragma unroll
    for (int r = 0; r < 4; r++) {
      int row = wm + ti * 16 + quad * 4 + r;
      float gb = g_[b * N_C + row];
#pragma unroll
      for (int tj = 0; tj < 4; tj++) {
        int col = n0 + wn + tj * 16 + cn;
        size_t idx = (size_t)(b * N_C + row) * S_HW + col;
        out[idx] = acc[ti][tj][r] + gb;
      }
    }
}

extern "C" void kernel_launch(void* const* d_in, const int* in_sizes, int n_in,
                              void* d_out, int out_size, void* d_ws,
                              size_t ws_size, hipStream_t stream) {
  const float* x = (const float*)d_in[0];
  const float* gn_w = (const float*)d_in[1];
  const float* gn_b = (const float*)d_in[2];
  const float* qkv_w = (const float*)d_in[3];
  const float* qkv_b = (const float*)d_in[4];
  const float* proj_w = (const float*)d_in[5];
  const float* proj_b = (const float*)d_in[6];
  float* out = (float*)d_out;  // reference output dtype is float32

  const size_t MB = 1ull << 20;
  char* ws = (char*)d_ws;
  bf16* ylo = (bf16*)ws;                              // 64 MB
  bf16* yt = (bf16*)(ws + 64 * MB);                   // 128 MB
  float* YG3 = (float*)(ws + 192 * MB);               // 4 MB (R1)
  bf16* FA = (bf16*)(ws + 194 * MB);                  // overlays YG3[2..4M)
  float* WkT = (float*)(ws + 196 * MB);               // 256 KB (R2)
  float* attn = (float*)(ws + 196 * MB + 256 * 1024); // 256 KB
  float* Sx = (float*)(ws + 196 * MB + 512 * 1024);   // 8 KB
  float* a_ = (float*)(ws + 196 * MB + 520 * 1024);   // 8 KB
  float* bv_ = (float*)(ws + 196 * MB + 528 * 1024);  // 8 KB
  float* u_ = (float*)(ws + 196 * MB + 536 * 1024);   // 16 KB
  float* vbe = (float*)(ws + 196 * MB + 552 * 1024);  // 8 KB
  float* g_ = (float*)(ws + 196 * MB + 560 * 1024);   // 8 KB
  float* T1 = (float*)(ws + 198 * MB);                // 2 MB (R3)
  bf16* yhi = (bf16*)d_out;  // 67 MB scratch in d_out; dead before k_final

  if (ws_size < 200 * MB) return;

  hipMemsetAsync(YG3, 0, 4 * MB + 520 * 1024, stream);
  k_split<<<dim3(256, 4, 8), 256, 0, stream>>>(x, yhi, ylo, yt, Sx);
  k_gram<<<dim3(16, 2, 8), 512, 0, stream>>>(yhi, ylo, YG3);
  k_wkt<<<256, 256, 0, stream>>>(qkv_w, WkT);
  k_coefs<<<dim3(8, 9), 256, 0, stream>>>(Sx, YG3, gn_w, gn_b, qkv_w, qkv_b,
                                          a_, bv_, u_, vbe);
  k_t1<<<dim3(16, 8), 256, 0, stream>>>(YG3, WkT, a_, bv_, Sx, T1);
  k_logits<<<dim3(8, 8), 256, 0, stream>>>(T1, qkv_w, qkv_b, u_, attn);
  k_pv<<<dim3(16, 8), 256, 0, stream>>>(proj_w, attn, qkv_w, a_, vbe, proj_b,
                                        FA, g_);
  k_final<<<dim3(128, 1, 8), 512, 0, stream>>>(FA, yt, g_, out);
}

// Round 10
// 501.989 us; speedup vs baseline: 1.0644x; 1.0258x over previous
//
#include <hip/hip_runtime.h>
#include <stdint.h>

typedef __bf16 bf16;
typedef __attribute__((ext_vector_type(8))) __bf16 bf16x8;
typedef __attribute__((ext_vector_type(4))) float f32x4;
typedef __attribute__((ext_vector_type(4))) unsigned u32x4;

#define S_HW 16384
#define N_C 256

__device__ __forceinline__ f32x4 mfma16(bf16x8 a, bf16x8 b, f32x4 c) {
  return __builtin_amdgcn_mfma_f32_16x16x32_bf16(a, b, c, 0, 0, 0);
}
__device__ __forceinline__ void async_ld16(const bf16* g, bf16* l) {
  __builtin_amdgcn_global_load_lds(
      (const __attribute__((address_space(1))) unsigned int*)g,
      (__attribute__((address_space(3))) unsigned int*)l, 16, 0, 0);
}
__device__ __forceinline__ unsigned short bf2u(bf16 h) {
  union { bf16 h; unsigned short u; } c; c.h = h; return c.u;
}

// K1 v3: split x (f32) -> y_hi[b][c][s] (ws), y_lo (ws), Sx. yt ELIMINATED
// (k_final now consumes yhi/ylo directly) -> write stream halved.
__global__ __launch_bounds__(256) void k_split(
    const float* __restrict__ x, bf16* __restrict__ yhi, bf16* __restrict__ ylo,
    float* __restrict__ Sx) {
  int b = blockIdx.z, c0 = blockIdx.y * 64, s0 = blockIdx.x * 64;
  __shared__ float sxl[256];
  int t = threadIdx.x;
  int cl = t >> 2, sg = t & 3;
  size_t off = (size_t)(b * N_C + c0 + cl) * S_HW + s0 + sg * 16;
  const float* xp = x + off;
  bf16x8 hv[2], lv[2];
  float sum = 0.f;
#pragma unroll
  for (int i2 = 0; i2 < 4; i2++) {
    float4 v = *(const float4*)(xp + i2 * 4);
    float f4[4] = {v.x, v.y, v.z, v.w};
#pragma unroll
    for (int k = 0; k < 4; k++) {
      int i = i2 * 4 + k;
      float fv = f4[k];
      bf16 h = (bf16)fv;
      bf16 l = (bf16)(fv - (float)h);
      hv[i >> 3][i & 7] = h;
      lv[i >> 3][i & 7] = l;
      sum += fv;
    }
  }
  *(bf16x8*)(yhi + off) = hv[0];
  *(bf16x8*)(yhi + off + 8) = hv[1];
  *(bf16x8*)(ylo + off) = lv[0];
  *(bf16x8*)(ylo + off + 8) = lv[1];
  sxl[t] = sum;
  __syncthreads();
  if (t < 64) {
    float s2 = sxl[t * 4] + sxl[t * 4 + 1] + sxl[t * 4 + 2] + sxl[t * 4 + 3];
    atomicAdd(&Sx[b * N_C + c0 + t], s2);
  }
}

// K2: Gram partials. YG3[b][c][r'] = sum_s hi_c[s]*y_{r'}[s] (r'<256:hi, else lo)
// (unchanged from R9; reads yhi from its new ws location)
__global__ __launch_bounds__(512, 2) void k_gram(
    const bf16* __restrict__ yhi, const bf16* __restrict__ ylo,
    float* __restrict__ YG3) {
  constexpr int BK = 64;
  constexpr int NT = 16;         // 1024 / BK
  constexpr int BUF = 256 * BK;  // 16384 elems = 32 KB
  __shared__ __align__(16) bf16 As[2 * BUF];  // 64 KB
  __shared__ __align__(16) bf16 Bs[2 * BUF];  // 64 KB
  int kc = blockIdx.x * 1024;
  int nsel = blockIdx.y;
  int b = blockIdx.z;
  int tid = threadIdx.x, lane = tid & 63, wave = tid >> 6;
  int wm = (wave >> 1) * 64, wn = (wave & 1) * 128;  // 4 M-waves x 2 N-waves
  const bf16* Ab = yhi + (size_t)(b * N_C) * S_HW;
  const bf16* Bb = (nsel == 0 ? yhi : ylo) + (size_t)(b * N_C) * S_HW;
  f32x4 acc[4][8] = {};
  int fm = lane & 15, cs = lane >> 4;

  auto STAGE = [&](int bi, int t) {
    int kt = kc + t * BK;
#pragma unroll
    for (int i = 0; i < 4; i++) {
      int ch = i * 512 + tid;
      int row = ch >> 3, slot = ch & 7;
      int gcol = (slot ^ (row & 7)) * 8;
      async_ld16(Ab + (size_t)row * S_HW + kt + gcol, As + bi * BUF + ch * 8);
      async_ld16(Bb + (size_t)row * S_HW + kt + gcol, Bs + bi * BUF + ch * 8);
    }
  };

  STAGE(0, 0);
  STAGE(1, 1);
  int cur = 0;
  for (int t = 0; t < NT; t++) {
    if (t < NT - 1)
      asm volatile("s_waitcnt vmcnt(8)" ::: "memory");
    else
      asm volatile("s_waitcnt vmcnt(0)" ::: "memory");
    __builtin_amdgcn_s_barrier();
    const bf16* Ap = As + cur * BUF;
    const bf16* Bp = Bs + cur * BUF;
    bf16x8 af[4][2], bfr[8][2];
#pragma unroll
    for (int q = 0; q < 4; q++) {
      int ra = wm + q * 16 + fm;
#pragma unroll
      for (int h = 0; h < 2; h++)
        af[q][h] =
            *(const bf16x8*)(Ap + ra * BK + (((h << 2) | cs) ^ (ra & 7)) * 8);
    }
#pragma unroll
    for (int p = 0; p < 8; p++) {
      int rb = wn + p * 16 + fm;
#pragma unroll
      for (int h = 0; h < 2; h++)
        bfr[p][h] =
            *(const bf16x8*)(Bp + rb * BK + (((h << 2) | cs) ^ (rb & 7)) * 8);
    }
    asm volatile("s_waitcnt lgkmcnt(0)" ::: "memory");
    __builtin_amdgcn_sched_barrier(0);
    __builtin_amdgcn_s_barrier();
    if (t + 2 < NT) STAGE(cur, t + 2);
    __builtin_amdgcn_sched_barrier(0);
    __builtin_amdgcn_s_setprio(1);
#pragma unroll
    for (int q = 0; q < 4; q++)
#pragma unroll
      for (int p = 0; p < 8; p++) {
        acc[q][p] = mfma16(af[q][0], bfr[p][0], acc[q][p]);
        acc[q][p] = mfma16(af[q][1], bfr[p][1], acc[q][p]);
      }
    __builtin_amdgcn_s_setprio(0);
    cur ^= 1;
  }
  int quad = lane >> 4, cn = lane & 15;
  float* yg = YG3 + (size_t)(b * N_C) * 512 + nsel * 256;
#pragma unroll
  for (int q = 0; q < 4; q++)
#pragma unroll
    for (int r = 0; r < 4; r++) {
      int m = wm + q * 16 + quad * 4 + r;
#pragma unroll
      for (int p = 0; p < 8; p++) {
        int n = wn + p * 16 + cn;
        atomicAdd(&yg[(size_t)m * 512 + n], acc[q][p][r]);
      }
    }
}

// K3: WkT[k][j] = qkv_w[(256+j)][k]
__global__ __launch_bounds__(256) void k_wkt(const float* __restrict__ qkv_w,
                                             float* __restrict__ WkT) {
  int k = blockIdx.x, j = threadIdx.x;
  WkT[k * 256 + j] = qkv_w[(256 + j) * 256 + k];
}

// K4: GN coefs a,b (role 0) + u rows (roles 1..8, 64 rows each).
__global__ __launch_bounds__(256) void k_coefs(
    const float* __restrict__ Sx, const float* __restrict__ YG3,
    const float* __restrict__ gn_w, const float* __restrict__ gn_b,
    const float* __restrict__ qkv_w, const float* __restrict__ qkv_b,
    float* __restrict__ a_, float* __restrict__ bv_, float* __restrict__ u_,
    float* __restrict__ vbe) {
  int b = blockIdx.x, role = blockIdx.y, t = threadIdx.x;
  __shared__ float sxl[256], gxd[256], gm[32], gr[32], sh[256], bl[256];
  __shared__ float ured[64][4];
  sxl[t] = Sx[b * N_C + t];
  gxd[t] = YG3[(size_t)(b * N_C + t) * 512 + t] +
           2.f * YG3[(size_t)(b * N_C + t) * 512 + 256 + t];
  __syncthreads();
  if (t < 32) {
    float s = 0.f, q2 = 0.f;
#pragma unroll
    for (int i = 0; i < 8; i++) { s += sxl[t * 8 + i]; q2 += gxd[t * 8 + i]; }
    float mean = s * (1.f / 131072.f);
    float var = q2 * (1.f / 131072.f) - mean * mean;
    gm[t] = mean;
    gr[t] = 1.f / sqrtf(var + 1e-5f);
  }
  __syncthreads();
  {
    float A = gn_w[t] * gr[t >> 3];
    float B = gn_b[t] - gm[t >> 3] * A;
    bl[t] = B;
    sh[t] = A * sxl[t] + 16384.f * B;
    if (role == 0) {
      a_[b * N_C + t] = A;
      bv_[b * N_C + t] = B;
    }
  }
  __syncthreads();
  if (role == 0) {
    const float* wp = qkv_w + (size_t)(512 + t) * 256;
    float acc = 0.f;
    for (int c = 0; c < 256; c++) acc += wp[c] * bl[c];
    vbe[b * N_C + t] = acc + qkv_b[512 + t];
  } else {
    int r = (role - 1) * 64 + (t >> 2);
    int seg = (t & 3) * 64;
    const float* wp = qkv_w + (size_t)r * 256 + seg;
    float p = 0.f;
    for (int c = 0; c < 64; c++) p += wp[c] * sh[seg + c];
    ured[t >> 2][t & 3] = p;
    __syncthreads();
    if (t < 64)
      u_[b * 512 + (role - 1) * 64 + t] =
          ured[t][0] + ured[t][1] + ured[t][2] + ured[t][3];
  }
}

// K5: T1[b] = G_h[b] * WkT, G_h assembled inline from YG3 + affine coefs.
__global__ __launch_bounds__(256) void k_t1(
    const float* __restrict__ YG3, const float* __restrict__ WkT,
    const float* __restrict__ a_, const float* __restrict__ bv_,
    const float* __restrict__ Sx, float* __restrict__ T1) {
  int tile = blockIdx.x, b = blockIdx.y;
  int i0 = (tile >> 2) * 64, j0 = (tile & 3) * 64;
  __shared__ float As[64][69];
  __shared__ float Bs[64][69];
  __shared__ float al[256], bl[256], sxl[256];
  int t = threadIdx.x;
  al[t] = a_[b * N_C + t];
  bl[t] = bv_[b * N_C + t];
  sxl[t] = Sx[b * N_C + t];
  int cl = t >> 2, qq = (t & 3) * 16;
  int kk = t >> 2, jj = (t & 3) * 16;
  int ti = t >> 4, tj = t & 15;
  float acc[4][4] = {};
  for (int kc = 0; kc < 256; kc += 64) {
    {  // A1: row part of Gx: hh + hl
      const float* yg = YG3 + (size_t)(b * N_C + i0 + cl) * 512 + kc + qq;
#pragma unroll
      for (int i = 0; i < 16; i++) As[cl][qq + i] = yg[i] + yg[256 + i];
    }
    __syncthreads();
    {  // A2: += lh (transposed hl)
      int cp = kc + kk;
      const float* ygp = YG3 + (size_t)(b * N_C + cp) * 512 + 256 + i0 + jj;
#pragma unroll
      for (int i = 0; i < 16; i++) As[jj + i][kk] += ygp[i];
    }
    __syncthreads();
    {  // A3: affine -> G_h
      int c = i0 + cl;
      float ac = al[c], bc = bl[c], sxc = sxl[c];
#pragma unroll
      for (int i = 0; i < 16; i++) {
        int cp = kc + qq + i;
        As[cl][qq + i] = ac * al[cp] * As[cl][qq + i] + ac * bl[cp] * sxc +
                         bc * al[cp] * sxl[cp] + 16384.f * bc * bl[cp];
      }
    }
    {  // B: WkT chunk
      const float* wp = WkT + (size_t)(kc + kk) * 256 + j0 + jj;
#pragma unroll
      for (int i = 0; i < 16; i += 4) {
        float4 v = *(const float4*)(wp + i);
        Bs[kk][jj + i] = v.x; Bs[kk][jj + i + 1] = v.y;
        Bs[kk][jj + i + 2] = v.z; Bs[kk][jj + i + 3] = v.w;
      }
    }
    __syncthreads();
    for (int k = 0; k < 64; k++) {
      float av[4], bv4[4];
#pragma unroll
      for (int ii = 0; ii < 4; ii++) av[ii] = As[ti * 4 + ii][k];
#pragma unroll
      for (int j2 = 0; j2 < 4; j2++) bv4[j2] = Bs[k][tj * 4 + j2];
#pragma unroll
      for (int ii = 0; ii < 4; ii++)
#pragma unroll
        for (int j2 = 0; j2 < 4; j2++) acc[ii][j2] += av[ii] * bv4[j2];
    }
    __syncthreads();
  }
#pragma unroll
  for (int ii = 0; ii < 4; ii++)
#pragma unroll
    for (int j2 = 0; j2 < 4; j2++)
      T1[(size_t)(b * N_C + i0 + ti * 4 + ii) * 256 + j0 + tj * 4 + j2] =
          acc[ii][j2];
}

// K6: logits (Wq*T1 cols + bias terms), softmax -> attn[b][h][32][32]
__global__ __launch_bounds__(256) void k_logits(
    const float* __restrict__ T1, const float* __restrict__ qkv_w,
    const float* __restrict__ qkv_b, const float* __restrict__ u_,
    float* __restrict__ attn) {
  int h = blockIdx.x, b = blockIdx.y;
  __shared__ float Tc[64][33];
  __shared__ float Wql[32][65];
  __shared__ float Ll[32][33];
  __shared__ float uq[32], uk[32], bq[32], bk[32];
  int t = threadIdx.x;
  if (t < 32) {
    uq[t] = u_[b * 512 + h * 32 + t];
    uk[t] = u_[b * 512 + 256 + h * 32 + t];
    bq[t] = qkv_b[h * 32 + t];
    bk[t] = qkv_b[256 + h * 32 + t];
  }
  int i = t & 31, jg = t >> 5;
  float acc[4] = {};
  for (int cc = 0; cc < 256; cc += 64) {
    {
      int c_l = t >> 2, seg = (t & 3) * 8;
      const float* tp = T1 + (size_t)(b * N_C + cc + c_l) * 256 + h * 32 + seg;
      float4 v0 = *(const float4*)tp, v1 = *(const float4*)(tp + 4);
      Tc[c_l][seg] = v0.x; Tc[c_l][seg + 1] = v0.y;
      Tc[c_l][seg + 2] = v0.z; Tc[c_l][seg + 3] = v0.w;
      Tc[c_l][seg + 4] = v1.x; Tc[c_l][seg + 5] = v1.y;
      Tc[c_l][seg + 6] = v1.z; Tc[c_l][seg + 7] = v1.w;
      int row = t >> 3, seg2 = (t & 7) * 8;
      const float* wp = qkv_w + (size_t)(h * 32 + row) * 256 + cc + seg2;
      float4 w0 = *(const float4*)wp, w1 = *(const float4*)(wp + 4);
      Wql[row][seg2] = w0.x; Wql[row][seg2 + 1] = w0.y;
      Wql[row][seg2 + 2] = w0.z; Wql[row][seg2 + 3] = w0.w;
      Wql[row][seg2 + 4] = w1.x; Wql[row][seg2 + 5] = w1.y;
      Wql[row][seg2 + 6] = w1.z; Wql[row][seg2 + 7] = w1.w;
    }
    __syncthreads();
    for (int c = 0; c < 64; c++) {
      float w = Wql[i][c];
#pragma unroll
      for (int j2 = 0; j2 < 4; j2++) acc[j2] += w * Tc[c][jg * 4 + j2];
    }
    __syncthreads();
  }
  const float scale = 0.17677669529663687f;
#pragma unroll
  for (int j2 = 0; j2 < 4; j2++) {
    int j = jg * 4 + j2;
    Ll[i][j] = scale * (acc[j2] + bq[i] * uk[j] + bk[j] * uq[i] +
                        16384.f * bq[i] * bk[j]);
  }
  __syncthreads();
  if (t < 32) {
    float m = -1e30f;
    for (int j = 0; j < 32; j++) m = fmaxf(m, Ll[t][j]);
    float e[32], s = 0.f;
    for (int j = 0; j < 32; j++) { e[j] = expf(Ll[t][j] - m); s += e[j]; }
    float inv = 1.f / s;
    float* ap = attn + (size_t)((b * 8 + h) * 32 + t) * 32;
    for (int j = 0; j < 32; j++) ap[j] = e[j] * inv;
  }
}

// K7 (fused k_m1+k_m2+k_fa): per 64x64 tile of M2 = (P*blockdiag(attn))*Wv,
// with As (=M1 tile) computed on the fly; epilogue applies diag(a), +I,
// hi/lo split -> FA; g = M1*vbe + proj_b accumulated during As production.
__global__ __launch_bounds__(256) void k_pv(
    const float* __restrict__ proj_w, const float* __restrict__ attn,
    const float* __restrict__ qkv_w, const float* __restrict__ a_,
    const float* __restrict__ vbe, const float* __restrict__ proj_b,
    bf16* __restrict__ FA, float* __restrict__ g_) {
  int tile = blockIdx.x, b = blockIdx.y;
  int i0 = (tile >> 2) * 64, j0 = (tile & 3) * 64;
  __shared__ float As[64][69];
  __shared__ float Bs[64][69];
  __shared__ float At[2][32][33];
  __shared__ float gred[64][4];
  int t = threadIdx.x;
  int cl = t >> 2, qq = (t & 3) * 16;
  int kk = t >> 2, jj = (t & 3) * 16;
  int ti = t >> 4, tj = t & 15;
  float acc[4][4] = {};
  float gacc = 0.f;
  for (int kc = 0; kc < 256; kc += 64) {
    int h0 = kc >> 5;
    __syncthreads();
    {  // stage attn (2 heads) + Bs (Wv chunk)
      const float* ap = attn + (size_t)b * 8192 + h0 * 1024;
#pragma unroll
      for (int i = 0; i < 8; i++) {
        int idx = t * 8 + i;
        At[idx >> 10][(idx >> 5) & 31][idx & 31] = ap[idx];
      }
      const float* wp = qkv_w + (size_t)(512 + kc + kk) * 256 + j0 + jj;
#pragma unroll
      for (int i = 0; i < 16; i += 4) {
        float4 v = *(const float4*)(wp + i);
        Bs[kk][jj + i] = v.x; Bs[kk][jj + i + 1] = v.y;
        Bs[kk][jj + i + 2] = v.z; Bs[kk][jj + i + 3] = v.w;
      }
    }
    __syncthreads();
    {  // As[cl][qq..qq+15] = M1 tile entries; accumulate g partials
      int hl = qq >> 5;
      int jbase = qq & 31;
      const float* pp = proj_w + (size_t)(i0 + cl) * 256 + (h0 + hl) * 32;
      float pr[32];
#pragma unroll
      for (int i = 0; i < 32; i += 4) {
        float4 v = *(const float4*)(pp + i);
        pr[i] = v.x; pr[i + 1] = v.y; pr[i + 2] = v.z; pr[i + 3] = v.w;
      }
#pragma unroll
      for (int i = 0; i < 16; i++) {
        int jm = jbase + i;
        float s = 0.f;
#pragma unroll
        for (int ii = 0; ii < 32; ii++) s += pr[ii] * At[hl][ii][jm];
        As[cl][qq + i] = s;
        gacc += s * vbe[b * N_C + kc + qq + i];
      }
    }
    __syncthreads();
    for (int k = 0; k < 64; k++) {
      float av[4], bv4[4];
#pragma unroll
      for (int ii = 0; ii < 4; ii++) av[ii] = As[ti * 4 + ii][k];
#pragma unroll
      for (int j2 = 0; j2 < 4; j2++) bv4[j2] = Bs[k][tj * 4 + j2];
#pragma unroll
      for (int ii = 0; ii < 4; ii++)
#pragma unroll
        for (int j2 = 0; j2 < 4; j2++) acc[ii][j2] += av[ii] * bv4[j2];
    }
  }
  __syncthreads();
  gred[cl][t & 3] = gacc;
  __syncthreads();
  if ((tile & 3) == 0 && t < 64)
    g_[b * N_C + i0 + t] =
        gred[t][0] + gred[t][1] + gred[t][2] + gred[t][3] + proj_b[i0 + t];
  float a4[4];
  {
    float4 v = *(const float4*)(a_ + b * N_C + j0 + tj * 4);
    a4[0] = v.x; a4[1] = v.y; a4[2] = v.z; a4[3] = v.w;
  }
#pragma unroll
  for (int ii = 0; ii < 4; ii++) {
    int row = i0 + ti * 4 + ii;
#pragma unroll
    for (int j2 = 0; j2 < 4; j2++) {
      int col = j0 + tj * 4 + j2;
      float f = acc[ii][j2] * a4[j2] + (row == col ? 1.0f : 0.0f);
      bf16 hi = (bf16)f;
      bf16 lo = (bf16)(f - (float)hi);
      FA[(size_t)(b * N_C + row) * 512 + col] = hi;
      FA[(size_t)(b * N_C + row) * 512 + 256 + col] = lo;
    }
  }
}

// K10 v4: out = (I+F)*y + g via 3-term hi/lo MFMA, B-operand staged from
// yhi/ylo ([c][s]) via reg-load + swizzled transposed ds_write (yt gone).
// A-side: FA via global_load_lds XOR-swizzle, 3-buffer counted vmcnt.
// B swizzle (both sides): slot' = slot ^ (s&7) ^ ((s>>3)&7).
// K-map: t<4: Fhi x yhi; 4<=t<8: Flo x yhi; t>=8: Fhi x ylo.
__global__ __launch_bounds__(512) void k_final(
    const bf16* __restrict__ FA, const bf16* __restrict__ yhi,
    const bf16* __restrict__ ylo, const float* __restrict__ g_,
    float* __restrict__ out) {
  constexpr int BK = 64;
  constexpr int NT = 12;          // 768 / BK
  constexpr int BUFA = 256 * BK;  // 32 KB per buffer
  __shared__ __align__(16) bf16 As[3 * BUFA];  // 96 KB
  __shared__ __align__(16) bf16 Bs[128 * BK];  // 16 KB single buffer
  int b = blockIdx.z, n0 = blockIdx.x * 128;
  int tid = threadIdx.x, lane = tid & 63, wave = tid >> 6;
  int wm = (wave >> 1) * 64, wn = (wave & 1) * 64;  // 4 M-waves x 2 N-waves
  const bf16* Ab = FA + (size_t)b * N_C * 512;
  f32x4 acc[4][4] = {};
  int fm = lane & 15, cs = lane >> 4;
  int cp = tid >> 4, sseg = (tid & 15) * 8;  // B-stage role: c-pair, s-segment

  auto STAGE_A = [&](int bi, int t) {
    int kt = t * BK;
    int ka = (kt < 512) ? kt : kt - 512;
#pragma unroll
    for (int i = 0; i < 4; i++) {
      int ch = i * 512 + tid;
      int row = ch >> 3, slot = ch & 7;
      int gcol = (slot ^ (row & 7)) * 8;
      async_ld16(Ab + (size_t)row * 512 + ka + gcol, As + bi * BUFA + ch * 8);
    }
  };
  auto BPTR = [&](int t) -> const bf16* {
    int kt = t * BK;
    const bf16* src = (kt < 512) ? yhi : ylo;
    int c0 = (kt < 256) ? kt : ((kt < 512) ? kt - 256 : kt - 512);
    return src + (size_t)(b * N_C + c0 + 2 * cp) * S_HW + n0 + sseg;
  };

  u32x4 r0, r1;
  {  // prologue: B(0) regs first, then A(0..2) stages (issue-order matters)
    const bf16* p = BPTR(0);
    r0 = *(const u32x4*)p;
    r1 = *(const u32x4*)(p + S_HW);
  }
  STAGE_A(0, 0);
  STAGE_A(1, 1);
  STAGE_A(2, 2);

  int slotW = cp >> 2, cw = (cp & 3) * 2;  // write-side slot / word offset
  for (int t = 0; t < NT; t++) {
    // wait: A(t) landed in LDS + B(t) regs arrived
    if (t == 0)
      asm volatile("s_waitcnt vmcnt(8)" ::: "memory");
    else if (t <= 9)
      asm volatile("s_waitcnt vmcnt(4)" ::: "memory");
    else
      asm volatile("s_waitcnt vmcnt(0)" ::: "memory");
    __builtin_amdgcn_s_barrier();  // A(t) visible; Bs reads of t-1 drained
    // transposed write of B(t) tile into Bs
#pragma unroll
    for (int i = 0; i < 8; i++) {
      int s = sseg + i;
      int sl2 = slotW ^ (s & 7) ^ ((s >> 3) & 7);
      unsigned h0 = (((const unsigned*)&r0)[i >> 1] >> ((i & 1) * 16)) & 0xffffu;
      unsigned h1 = (((const unsigned*)&r1)[i >> 1] >> ((i & 1) * 16)) & 0xffffu;
      *(unsigned*)(Bs + s * 64 + sl2 * 8 + cw) = h0 | (h1 << 16);
    }
    asm volatile("s_waitcnt lgkmcnt(0)" ::: "memory");
    __builtin_amdgcn_s_barrier();  // Bs(t) visible to all waves
    // fragment reads
    const bf16* Ap = As + (t % 3) * BUFA;
    bf16x8 af[4][2], bfr[4][2];
#pragma unroll
    for (int q = 0; q < 4; q++) {
      int ra = wm + q * 16 + fm;
      int rb = wn + q * 16 + fm;
#pragma unroll
      for (int h = 0; h < 2; h++) {
        int slot = (h << 2) | cs;
        af[q][h] = *(const bf16x8*)(Ap + ra * BK + (slot ^ (ra & 7)) * 8);
        bfr[q][h] = *(const bf16x8*)(
            Bs + rb * 64 + (slot ^ (rb & 7) ^ ((rb >> 3) & 7)) * 8);
      }
    }
    asm volatile("s_waitcnt lgkmcnt(0)" ::: "memory");
    __builtin_amdgcn_sched_barrier(0);
    __builtin_amdgcn_s_barrier();  // all frag reads drained before restage
    if (t + 1 < NT) {  // issue B(t+1) regs FIRST (vmcnt accounting)
      const bf16* p = BPTR(t + 1);
      r0 = *(const u32x4*)p;
      r1 = *(const u32x4*)(p + S_HW);
    }
    if (t + 3 < NT) STAGE_A((t + 3) % 3, t + 3);
    __builtin_amdgcn_sched_barrier(0);
    __builtin_amdgcn_s_setprio(1);
#pragma unroll
    for (int ti = 0; ti < 4; ti++)
#pragma unroll
      for (int tj = 0; tj < 4; tj++) {
        acc[ti][tj] = mfma16(af[ti][0], bfr[tj][0], acc[ti][tj]);
        acc[ti][tj] = mfma16(af[ti][1], bfr[tj][1], acc[ti][tj]);
      }
    __builtin_amdgcn_s_setprio(0);
  }
  int quad = lane >> 4, cn = lane & 15;
#pragma unroll
  for (int ti = 0; ti < 4; ti++)
#pragma unroll
    for (int r = 0; r < 4; r++) {
      int row = wm + ti * 16 + quad * 4 + r;
      float gb = g_[b * N_C + row];
#pragma unroll
      for (int tj = 0; tj < 4; tj++) {
        int col = n0 + wn + tj * 16 + cn;
        size_t idx = (size_t)(b * N_C + row) * S_HW + col;
        out[idx] = acc[ti][tj][r] + gb;
      }
    }
}

extern "C" void kernel_launch(void* const* d_in, const int* in_sizes, int n_in,
                              void* d_out, int out_size, void* d_ws,
                              size_t ws_size, hipStream_t stream) {
  const float* x = (const float*)d_in[0];
  const float* gn_w = (const float*)d_in[1];
  const float* gn_b = (const float*)d_in[2];
  const float* qkv_w = (const float*)d_in[3];
  const float* qkv_b = (const float*)d_in[4];
  const float* proj_w = (const float*)d_in[5];
  const float* proj_b = (const float*)d_in[6];
  float* out = (float*)d_out;  // reference output dtype is float32

  const size_t MB = 1ull << 20;
  char* ws = (char*)d_ws;
  bf16* ylo = (bf16*)ws;                              // 64 MB
  bf16* yhi = (bf16*)(ws + 64 * MB);                  // 64 MB (yt eliminated)
  float* YG3 = (float*)(ws + 192 * MB);               // 4 MB (R1)
  bf16* FA = (bf16*)(ws + 194 * MB);                  // overlays YG3[2..4M)
  float* WkT = (float*)(ws + 196 * MB);               // 256 KB (R2)
  float* attn = (float*)(ws + 196 * MB + 256 * 1024); // 256 KB
  float* Sx = (float*)(ws + 196 * MB + 512 * 1024);   // 8 KB
  float* a_ = (float*)(ws + 196 * MB + 520 * 1024);   // 8 KB
  float* bv_ = (float*)(ws + 196 * MB + 528 * 1024);  // 8 KB
  float* u_ = (float*)(ws + 196 * MB + 536 * 1024);   // 16 KB
  float* vbe = (float*)(ws + 196 * MB + 552 * 1024);  // 8 KB
  float* g_ = (float*)(ws + 196 * MB + 560 * 1024);   // 8 KB
  float* T1 = (float*)(ws + 198 * MB);                // 2 MB (R3)

  if (ws_size < 200 * MB) return;

  hipMemsetAsync(YG3, 0, 4 * MB + 520 * 1024, stream);
  k_split<<<dim3(256, 4, 8), 256, 0, stream>>>(x, yhi, ylo, Sx);
  k_gram<<<dim3(16, 2, 8), 512, 0, stream>>>(yhi, ylo, YG3);
  k_wkt<<<256, 256, 0, stream>>>(qkv_w, WkT);
  k_coefs<<<dim3(8, 9), 256, 0, stream>>>(Sx, YG3, gn_w, gn_b, qkv_w, qkv_b,
                                          a_, bv_, u_, vbe);
  k_t1<<<dim3(16, 8), 256, 0, stream>>>(YG3, WkT, a_, bv_, Sx, T1);
  k_logits<<<dim3(8, 8), 256, 0, stream>>>(T1, qkv_w, qkv_b, u_, attn);
  k_pv<<<dim3(16, 8), 256, 0, stream>>>(proj_w, attn, qkv_w, a_, vbe, proj_b,
                                        FA, g_);
  k_final<<<dim3(128, 1, 8), 512, 0, stream>>>(FA, yhi, ylo, g_, out);
}